// Round 1
// baseline (363.308 us; speedup 1.0000x reference)
//
#include <hip/hip_runtime.h>
#include <stdint.h>

#define NNODES 50000
#define NEDGES 400000
#define INCH 7
#define EMB 128
#define EDIM 6
#define KD 896          // INCH*EMB
#define BM 128          // edges per block
#define NSTEPS 28       // KD/32

typedef __attribute__((ext_vector_type(8))) short bf16x8;
typedef __attribute__((ext_vector_type(4))) float f32x4;

__device__ __forceinline__ short f2bf(float f) {
  union { float f; uint32_t u; } v; v.f = f;
  uint32_t r = v.u + 0x7FFFu + ((v.u >> 16) & 1u);
  return (short)(r >> 16);
}

// Build B[o][i*128+k] = W2[k][i*128+o] in bf16.  [128][896] bf16, row stride 1792B.
__global__ void prep_B(const float* __restrict__ W2, short* __restrict__ Bg) {
  int idx = blockIdx.x * 256 + threadIdx.x;       // 448 blocks * 256 = 114688 exact
  int o = idx / KD;
  int c = idx - o * KD;
  int i = c >> 7, k = c & 127;
  Bg[idx] = f2bf(W2[k * KD + (i << 7) + o]);
}

__device__ __forceinline__ void stageB(short* dstB, const short* __restrict__ Bg,
                                       int step, int w, int lane) {
  // wave w loads B rows [w*32, w*32+32), cols [step*32, step*32+32) (64B/row)
#pragma unroll
  for (int j = 0; j < 2; ++j) {
    const int row = w * 32 + j * 16 + (lane >> 2);
    const char* g = (const char*)Bg + (size_t)row * (KD * 2) + step * 64 + (lane & 3) * 16;
    char* l = (char*)dstB + (w * 32 + j * 16) * 64;   // wave-uniform base; HW adds lane*16
    __builtin_amdgcn_global_load_lds((const __attribute__((address_space(1))) void*)g,
                                     (__attribute__((address_space(3))) void*)l,
                                     16, 0, 0);
  }
}

__global__ __launch_bounds__(256, 2)
void nnconv_main(const float* __restrict__ x,
                 const int* __restrict__ ei,
                 const float* __restrict__ ea,
                 const float* __restrict__ W1,
                 const float* __restrict__ b1,
                 const float* __restrict__ b2,
                 const short* __restrict__ Bg,
                 float* __restrict__ cnt,
                 float* __restrict__ out) {
  __shared__ __align__(16) short h_s[BM * EMB];       // 32KB, XOR-swizzled rows
  __shared__ __align__(16) short B_s[2][EMB * 32];    // 2 x 8KB, [row n][32 k] bf16
  __shared__ __align__(16) float x_s[BM][8];          // gathered x[src], 7 used
  __shared__ __align__(16) float ea_s[BM * EDIM];
  __shared__ __align__(16) float w1_s[EDIM * EMB];
  __shared__ __align__(16) float b1_s[EMB];
  __shared__ __align__(16) float b2_s[KD];
  __shared__ int dst_s[BM];

  const int t = threadIdx.x;
  const int lane = t & 63;
  const int w = t >> 6;
  const int eb = blockIdx.x * BM;

  // ---- phase 0: coalesced staging + x gather ----
  if (t < 192) {
    *(float4*)&ea_s[t * 4] = *(const float4*)&ea[(size_t)eb * EDIM + t * 4];
    *(float4*)&w1_s[t * 4] = *(const float4*)&W1[t * 4];
  }
  if (t >= 192 && t < 224) { int q = t - 192; *(float4*)&b1_s[q * 4] = *(const float4*)&b1[q * 4]; }
  if (t < 224) *(float4*)&b2_s[t * 4] = *(const float4*)&b2[t * 4];
  if (t < BM) {
    int s = ei[eb + t];
    int d = ei[NEDGES + eb + t];
    dst_s[t] = d;
#pragma unroll
    for (int i = 0; i < 7; ++i) x_s[t][i] = x[s * 7 + i];
    atomicAdd(&cnt[d], 1.0f);
  }
  stageB(&B_s[0][0], Bg, 0, w, lane);   // prefetch K-step 0
  __syncthreads();

  // ---- phase 1: h = gelu(ea@W1+b1) -> bf16 LDS (swizzled) ----
  {
    const int e = t >> 1, half = t & 1;
    float a[6];
#pragma unroll
    for (int q = 0; q < 6; ++q) a[q] = ea_s[e * 6 + q];
    const int swz = (e & 7) << 4;
#pragma unroll
    for (int j = 0; j < 8; ++j) {
      bf16x8 hv;
#pragma unroll
      for (int m = 0; m < 8; ++m) {
        int c = half * 64 + j * 8 + m;
        float pre = b1_s[c];
#pragma unroll
        for (int q = 0; q < 6; ++q) pre += a[q] * w1_s[q * EMB + c];
        float g = 0.5f * pre * (1.0f + erff(pre * 0.70710678118f));
        hv[m] = f2bf(g);
      }
      int addr = e * 256 + ((half * 128 + j * 16) ^ swz);
      *(bf16x8*)((char*)h_s + addr) = hv;
    }
  }
  asm volatile("s_waitcnt vmcnt(0)" ::: "memory");
  __syncthreads();

  // ---- K-loop: for i in 0..6:  tmp = h @ W2_i (MFMA, K=128); acc += x_i * tmp ----
  const int wm = w >> 1, wn = w & 1;      // 2x2 wave grid over 128x128 tile
  const int rowA = lane & 15;
  const int kseg = lane >> 4;

  f32x4 acc[4][4];
#pragma unroll
  for (int fm = 0; fm < 4; ++fm)
#pragma unroll
    for (int fn = 0; fn < 4; ++fn) acc[fm][fn] = f32x4{0.f, 0.f, 0.f, 0.f};

  int cur = 0;
#pragma unroll 1
  for (int i = 0; i < 7; ++i) {
    f32x4 tmp[4][4];
#pragma unroll
    for (int fm = 0; fm < 4; ++fm)
#pragma unroll
      for (int fn = 0; fn < 4; ++fn) tmp[fm][fn] = f32x4{0.f, 0.f, 0.f, 0.f};

#pragma unroll
    for (int kk = 0; kk < 4; ++kk) {
      const int step = i * 4 + kk;
      if (step < NSTEPS - 1) stageB(&B_s[cur ^ 1][0], Bg, step + 1, w, lane);

      bf16x8 af[4], bfr[4];
#pragma unroll
      for (int fm = 0; fm < 4; ++fm) {
        int row = wm * 64 + fm * 16 + rowA;
        int col = (kk * 64 + kseg * 16) ^ ((row & 7) << 4);
        af[fm] = *(const bf16x8*)((const char*)h_s + row * 256 + col);
      }
#pragma unroll
      for (int fn = 0; fn < 4; ++fn) {
        int n = wn * 64 + fn * 16 + rowA;
        bfr[fn] = *(const bf16x8*)((const char*)&B_s[cur][0] + n * 64 + kseg * 16);
      }
#pragma unroll
      for (int fm = 0; fm < 4; ++fm)
#pragma unroll
        for (int fn = 0; fn < 4; ++fn)
          tmp[fm][fn] = __builtin_amdgcn_mfma_f32_16x16x32_bf16(af[fm], bfr[fn], tmp[fm][fn], 0, 0, 0);

      asm volatile("s_waitcnt vmcnt(0)" ::: "memory");
      __syncthreads();
      cur ^= 1;
    }
    // acc += x[:,i] * tmp   (C/D layout: col=lane&15, row=kseg*4+r)
#pragma unroll
    for (int fm = 0; fm < 4; ++fm) {
#pragma unroll
      for (int r = 0; r < 4; ++r) {
        float xv = x_s[wm * 64 + fm * 16 + kseg * 4 + r][i];
#pragma unroll
        for (int fn = 0; fn < 4; ++fn) acc[fm][fn][r] += xv * tmp[fm][fn][r];
      }
    }
  }

  // ---- epilogue: + x·b2 bias term, then atomic scatter to out[dst] ----
  const int colA = rowA;
  float bb[4][7];
#pragma unroll
  for (int fn = 0; fn < 4; ++fn)
#pragma unroll
    for (int i = 0; i < 7; ++i) bb[fn][i] = b2_s[i * EMB + wn * 64 + fn * 16 + colA];

#pragma unroll
  for (int fm = 0; fm < 4; ++fm) {
#pragma unroll
    for (int r = 0; r < 4; ++r) {
      const int row = wm * 64 + fm * 16 + kseg * 4 + r;
      float xr[7];
#pragma unroll
      for (int i = 0; i < 7; ++i) xr[i] = x_s[row][i];
      const int d = dst_s[row];
      float* op = out + (size_t)d * EMB + wn * 64 + colA;
#pragma unroll
      for (int fn = 0; fn < 4; ++fn) {
        float v = acc[fm][fn][r];
#pragma unroll
        for (int i = 0; i < 7; ++i) v += xr[i] * bb[fn][i];
        atomicAdd(op + fn * 16, v);
      }
    }
  }
}

// out = out/clip(cnt,1) + x@root + bias
__global__ void finalize(const float* __restrict__ x, const float* __restrict__ root,
                         const float* __restrict__ bias, const float* __restrict__ cnt,
                         float* __restrict__ out) {
  int idx = blockIdx.x * 256 + threadIdx.x;
  int n = idx >> 7, o = idx & 127;
  float c = fmaxf(cnt[n], 1.0f);
  float v = out[idx] / c + bias[o];
#pragma unroll
  for (int i = 0; i < 7; ++i) v += x[n * 7 + i] * root[i * EMB + o];
  out[idx] = v;
}

extern "C" void kernel_launch(void* const* d_in, const int* in_sizes, int n_in,
                              void* d_out, int out_size, void* d_ws, size_t ws_size,
                              hipStream_t stream) {
  const float* x    = (const float*)d_in[0];
  const int*   ei   = (const int*)d_in[1];
  const float* ea   = (const float*)d_in[2];
  const float* W1   = (const float*)d_in[3];
  const float* b1   = (const float*)d_in[4];
  const float* W2   = (const float*)d_in[5];
  const float* b2   = (const float*)d_in[6];
  const float* root = (const float*)d_in[7];
  const float* bias = (const float*)d_in[8];
  float* out = (float*)d_out;

  short* Bg  = (short*)d_ws;                               // 128*896*2 = 229376 B
  float* cnt = (float*)((char*)d_ws + 128 * KD * 2);       // 50000 floats

  hipMemsetAsync(out, 0, (size_t)NNODES * EMB * sizeof(float), stream);
  hipMemsetAsync(cnt, 0, (size_t)NNODES * sizeof(float), stream);
  prep_B<<<448, 256, 0, stream>>>(W2, Bg);
  nnconv_main<<<NEDGES / BM, 256, 0, stream>>>(x, ei, ea, W1, b1, b2, Bg, cnt, out);
  finalize<<<NNODES * EMB / 256, 256, 0, stream>>>(x, root, bias, cnt, out);
}

// Round 2
// 313.127 us; speedup vs baseline: 1.1603x; 1.1603x over previous
//
#include <hip/hip_runtime.h>
#include <stdint.h>

#define NNODES 50000
#define NEDGES 400000
#define INCH 7
#define EMB 128
#define EDIM 6
#define KD 896          // INCH*EMB
#define BM 128          // edges per block
#define NSTEPS 28       // KD/32

typedef __attribute__((ext_vector_type(8))) short bf16x8;
typedef __attribute__((ext_vector_type(4))) float f32x4;

__device__ __forceinline__ short f2bf(float f) {
  union { float f; uint32_t u; } v; v.f = f;
  uint32_t r = v.u + 0x7FFFu + ((v.u >> 16) & 1u);
  return (short)(r >> 16);
}

__device__ __forceinline__ float fast_gelu(float x) {
  // tanh-form GELU; |err| vs erf-form < 1e-3, below bf16 rounding of h
  float x2 = x * x;
  float y = x * (0.7978845608f + 0.03567740814f * x2);
  float e = __expf(2.0f * y);             // v_exp_f32 path
  float t = 1.0f - 2.0f / (1.0f + e);     // tanh(y), saturates correctly
  return 0.5f * x * (1.0f + t);
}

// Bp layout (bf16 shorts), fragment-order so a wave's B-load is 64 lanes x 16B
// contiguous:  F = (step*8 + nh)*512 + kseg*128 + r*8 + m
//   step = i*4+kk (K-step of 32), nh = o>>4 (0..7), r = o&15, m = k within 8
//   value = W2[(kk*32 + kseg*8 + m)*896 + i*128 + nh*16 + r]
__global__ void prep_B(const float* __restrict__ W2, short* __restrict__ Bp) {
  int idx = blockIdx.x * 256 + threadIdx.x;   // 448*256 = 114688 exact
  int m    = idx & 7;
  int r    = (idx >> 3) & 15;
  int kseg = (idx >> 7) & 3;
  int nh   = (idx >> 9) & 7;
  int step = idx >> 12;
  int i = step >> 2, kk = step & 3;
  int k = kk * 32 + kseg * 8 + m;
  int o = nh * 16 + r;
  Bp[idx] = f2bf(W2[k * KD + i * EMB + o]);
}

__global__ __launch_bounds__(256, 2)
void nnconv_main(const float* __restrict__ x,
                 const int* __restrict__ ei,
                 const float* __restrict__ ea,
                 const float* __restrict__ W1,
                 const float* __restrict__ b1,
                 const float* __restrict__ b2,
                 const short* __restrict__ Bp,
                 float* __restrict__ cnt,
                 float* __restrict__ out) {
  __shared__ __align__(16) short h_s[BM * EMB];   // 32KB, 4-bit XOR swizzled rows
  __shared__ __align__(16) float x_s[BM][9];      // padded: kills 4-way conflict
  __shared__ __align__(16) float ea_s[BM * EDIM];
  __shared__ __align__(16) float w1_s[EDIM * EMB];
  __shared__ __align__(16) float b1_s[EMB];
  __shared__ __align__(16) float b2_s[KD];
  __shared__ int dst_s[BM];

  const int t = threadIdx.x;
  const int lane = t & 63;
  const int w = t >> 6;
  const int eb = blockIdx.x * BM;

  // ---- phase 0: coalesced staging + x gather ----
  if (t < 192) {
    *(float4*)&ea_s[t * 4] = *(const float4*)&ea[(size_t)eb * EDIM + t * 4];
    *(float4*)&w1_s[t * 4] = *(const float4*)&W1[t * 4];
  }
  if (t >= 192 && t < 224) { int q = t - 192; *(float4*)&b1_s[q * 4] = *(const float4*)&b1[q * 4]; }
  if (t < 224) *(float4*)&b2_s[t * 4] = *(const float4*)&b2[t * 4];
  if (t < BM) {
    int s = ei[eb + t];
    int d = ei[NEDGES + eb + t];
    dst_s[t] = d;
#pragma unroll
    for (int i = 0; i < 7; ++i) x_s[t][i] = x[s * 7 + i];
    atomicAdd(&cnt[d], 1.0f);
  }
  __syncthreads();

  // ---- phase 1: h = gelu(ea@W1+b1) -> bf16 LDS (swizzled) ----
  {
    const int e = t >> 1, half = t & 1;
    float a[6];
#pragma unroll
    for (int q = 0; q < 6; ++q) a[q] = ea_s[e * 6 + q];
    const int swz = (e & 15) << 4;
#pragma unroll
    for (int j = 0; j < 8; ++j) {
      bf16x8 hv;
#pragma unroll
      for (int m = 0; m < 8; ++m) {
        int c = half * 64 + j * 8 + m;
        float pre = b1_s[c];
#pragma unroll
        for (int q = 0; q < 6; ++q) pre += a[q] * w1_s[q * EMB + c];
        hv[m] = f2bf(fast_gelu(pre));
      }
      int addr = e * 256 + ((half * 128 + j * 16) ^ swz);
      *(bf16x8*)((char*)h_s + addr) = hv;
    }
  }
  __syncthreads();

  // ---- K-loop: barrier-free. B fragments stream global->reg (L2-resident),
  //      distance-1 prefetch hidden under 16 MFMAs per step. ----
  const int wm = w >> 1, wn = w & 1;      // 2x2 wave grid over 128x128 tile
  const int rowA = lane & 15;
  const int kseg = lane >> 4;
  const char* BpByte = (const char*)Bp + (size_t)lane * 16;

  f32x4 acc[4][4];
#pragma unroll
  for (int fm = 0; fm < 4; ++fm)
#pragma unroll
    for (int fn = 0; fn < 4; ++fn) acc[fm][fn] = f32x4{0.f, 0.f, 0.f, 0.f};

  bf16x8 bcur[4], bnxt[4];
#pragma unroll
  for (int fn = 0; fn < 4; ++fn)
    bcur[fn] = *(const bf16x8*)(BpByte + ((0 * 8 + wn * 4 + fn) << 10));

#pragma unroll 1
  for (int i = 0; i < 7; ++i) {
    f32x4 tmp[4][4];
#pragma unroll
    for (int fm = 0; fm < 4; ++fm)
#pragma unroll
      for (int fn = 0; fn < 4; ++fn) tmp[fm][fn] = f32x4{0.f, 0.f, 0.f, 0.f};

#pragma unroll
    for (int kk = 0; kk < 4; ++kk) {
      const int step = i * 4 + kk;
      if (step < NSTEPS - 1) {
#pragma unroll
        for (int fn = 0; fn < 4; ++fn)
          bnxt[fn] = *(const bf16x8*)(BpByte + (((step + 1) * 8 + wn * 4 + fn) << 10));
      }
      bf16x8 af[4];
#pragma unroll
      for (int fm = 0; fm < 4; ++fm) {
        int row = wm * 64 + fm * 16 + rowA;
        int col = (kk * 64 + kseg * 16) ^ ((row & 15) << 4);
        af[fm] = *(const bf16x8*)((const char*)h_s + row * 256 + col);
      }
#pragma unroll
      for (int fm = 0; fm < 4; ++fm)
#pragma unroll
        for (int fn = 0; fn < 4; ++fn)
          tmp[fm][fn] = __builtin_amdgcn_mfma_f32_16x16x32_bf16(af[fm], bcur[fn], tmp[fm][fn], 0, 0, 0);
#pragma unroll
      for (int fn = 0; fn < 4; ++fn) bcur[fn] = bnxt[fn];
    }
    // acc += x[:,i] * tmp   (C/D layout: col=lane&15, row=kseg*4+r)
#pragma unroll
    for (int fm = 0; fm < 4; ++fm) {
#pragma unroll
      for (int r = 0; r < 4; ++r) {
        float xv = x_s[wm * 64 + fm * 16 + kseg * 4 + r][i];
#pragma unroll
        for (int fn = 0; fn < 4; ++fn) acc[fm][fn][r] += xv * tmp[fm][fn][r];
      }
    }
  }

  // ---- epilogue: + x·b2 bias term, then atomic scatter to out[dst] ----
  const int colA = rowA;
  float bb[4][7];
#pragma unroll
  for (int fn = 0; fn < 4; ++fn)
#pragma unroll
    for (int i = 0; i < 7; ++i) bb[fn][i] = b2_s[i * EMB + wn * 64 + fn * 16 + colA];

#pragma unroll
  for (int fm = 0; fm < 4; ++fm) {
#pragma unroll
    for (int r = 0; r < 4; ++r) {
      const int row = wm * 64 + fm * 16 + kseg * 4 + r;
      float xr[7];
#pragma unroll
      for (int i = 0; i < 7; ++i) xr[i] = x_s[row][i];
      const int d = dst_s[row];
      float* op = out + (size_t)d * EMB + wn * 64 + colA;
#pragma unroll
      for (int fn = 0; fn < 4; ++fn) {
        float v = acc[fm][fn][r];
#pragma unroll
        for (int i = 0; i < 7; ++i) v += xr[i] * bb[fn][i];
        atomicAdd(op + fn * 16, v);
      }
    }
  }
}

// out = out/clip(cnt,1) + x@root + bias
__global__ void finalize(const float* __restrict__ x, const float* __restrict__ root,
                         const float* __restrict__ bias, const float* __restrict__ cnt,
                         float* __restrict__ out) {
  int idx = blockIdx.x * 256 + threadIdx.x;
  int n = idx >> 7, o = idx & 127;
  float c = fmaxf(cnt[n], 1.0f);
  float v = out[idx] / c + bias[o];
#pragma unroll
  for (int i = 0; i < 7; ++i) v += x[n * 7 + i] * root[i * EMB + o];
  out[idx] = v;
}

extern "C" void kernel_launch(void* const* d_in, const int* in_sizes, int n_in,
                              void* d_out, int out_size, void* d_ws, size_t ws_size,
                              hipStream_t stream) {
  const float* x    = (const float*)d_in[0];
  const int*   ei   = (const int*)d_in[1];
  const float* ea   = (const float*)d_in[2];
  const float* W1   = (const float*)d_in[3];
  const float* b1   = (const float*)d_in[4];
  const float* W2   = (const float*)d_in[5];
  const float* b2   = (const float*)d_in[6];
  const float* root = (const float*)d_in[7];
  const float* bias = (const float*)d_in[8];
  float* out = (float*)d_out;

  short* Bp  = (short*)d_ws;                               // 128*896*2 = 229376 B
  float* cnt = (float*)((char*)d_ws + 128 * KD * 2);       // 50000 floats

  hipMemsetAsync(out, 0, (size_t)NNODES * EMB * sizeof(float), stream);
  hipMemsetAsync(cnt, 0, (size_t)NNODES * sizeof(float), stream);
  prep_B<<<448, 256, 0, stream>>>(W2, Bp);
  nnconv_main<<<NEDGES / BM, 256, 0, stream>>>(x, ei, ea, W1, b1, b2, Bp, cnt, out);
  finalize<<<NNODES * EMB / 256, 256, 0, stream>>>(x, root, bias, cnt, out);
}